// Round 7
// baseline (52.429 us; speedup 1.0000x reference)
//
#include <hip/hip_runtime.h>

// Integrate-and-fire scan: x (T*B, C, H, W) f32, T=8, viewed as (T, N).
// One thread per float4 column (R4 structure: exact-fit grid, best so far).
//
// R6 theory: input(128MiB)+output(128MiB) = 256MiB = exactly L3 size; they
// split it 50/50 (FETCH pinned at 64MiB) and all 128MiB of output writes
// reach HBM every replay. FLIP the resident set: nt LOADS keep the input
// from allocating in the MALL -> the output becomes the sole resident set;
// since every output line is re-written each replay, stores hit dirty MALL
// lines and (almost) never write back to HBM. Traffic becomes read-
// dominated (~134MB read, ~0 write). nt loads are coherence-safe: input is
// never written during timing, so there are no dirty input lines to miss.

#define T_STEPS 8

typedef float f32x4 __attribute__((ext_vector_type(4)));

__global__ __launch_bounds__(256) void if_scan_kernel(
    const f32x4* __restrict__ x,
    const float* __restrict__ thr_p,
    f32x4* __restrict__ out,
    int n4)   // N/4 vec4 elements per timestep
{
    const int i = blockIdx.x * blockDim.x + threadIdx.x;
    if (i >= n4) return;
    const float th = thr_p[0];

    // 8 independent nontemporal loads issued up front: full MLP, and no
    // MALL allocation so the output owns the L3.
    f32x4 xs[T_STEPS];
    #pragma unroll
    for (int t = 0; t < T_STEPS; ++t) {
        xs[t] = __builtin_nontemporal_load(&x[(size_t)t * n4 + i]);
    }

    f32x4 mem = {0.f, 0.f, 0.f, 0.f};
    #pragma unroll
    for (int t = 0; t < T_STEPS; ++t) {
        f32x4 s;
        mem += xs[t];                                   // integrate
        #pragma unroll
        for (int j = 0; j < 4; ++j) {
            s[j]   = (mem[j] - th > 0.f) ? 1.f : 0.f;   // fire
            mem[j] = (s[j] != 0.f) ? 0.f : mem[j];      // hard reset
        }
        // NORMAL (cached) store: we WANT output lines resident in the MALL
        // so next replay's stores hit them and skip HBM writeback.
        out[(size_t)t * n4 + i] = s;
    }
}

extern "C" void kernel_launch(void* const* d_in, const int* in_sizes, int n_in,
                              void* d_out, int out_size, void* d_ws, size_t ws_size,
                              hipStream_t stream) {
    const float* x   = (const float*)d_in[0];
    const float* thr = (const float*)d_in[1];
    float* out       = (float*)d_out;

    const int total = in_sizes[0];       // T*B*C*H*W = 33,554,432
    const int N     = total / T_STEPS;   // per-timestep elements = 4,194,304
    const int n4    = N / 4;             // vec4 count = 1,048,576

    const int threads = 256;
    const int blocks  = (n4 + threads - 1) / threads;   // 4096: exact fit

    if_scan_kernel<<<blocks, threads, 0, stream>>>(
        (const f32x4*)x, thr, (f32x4*)out, n4);
}

// Round 8
// 47.190 us; speedup vs baseline: 1.1110x; 1.1110x over previous
//
#include <hip/hip_runtime.h>

// Integrate-and-fire scan: x (T*B, C, H, W) f32, T=8, viewed as (T, N).
// R7 lesson: nt loads regressed; fillBuffer proved writes can do 7.2 TB/s,
// so we're mixed-stream limited, not write-limited. R4 (1 col/thread,
// exact grid, nt stores) = 46.7 us = 91% of copy-equivalent ceiling.
//
// This round: wave-adjacent 2 columns/thread for DRAM page locality.
// Wave w covers vec4 columns [w*128+lane] and [w*128+64+lane]: each
// timestep's two load (and store) instructions are back-to-back 1 KB
// contiguous -> 2 KB sequential per wave per stream, perfectly coalesced.

#define T_STEPS 8

typedef float f32x4 __attribute__((ext_vector_type(4)));

__global__ __launch_bounds__(256) void if_scan_kernel(
    const f32x4* __restrict__ x,
    const float* __restrict__ thr_p,
    f32x4* __restrict__ out,
    int n4)   // N/4 vec4 elements per timestep
{
    const int tid  = blockIdx.x * blockDim.x + threadIdx.x;
    const int wave = tid >> 6;
    const int lane = tid & 63;
    const int i0   = wave * 128 + lane;      // first 1 KB chunk of this wave
    const int i1   = i0 + 64;                // adjacent 1 KB chunk
    if (i1 >= n4) return;                    // (exact fit: never taken)
    const float th = thr_p[0];

    f32x4 xa[T_STEPS], xb[T_STEPS];
    #pragma unroll
    for (int t = 0; t < T_STEPS; ++t) {
        xa[t] = x[(size_t)t * n4 + i0];
        xb[t] = x[(size_t)t * n4 + i1];
    }

    f32x4 ma = {0.f, 0.f, 0.f, 0.f};
    f32x4 mb = {0.f, 0.f, 0.f, 0.f};
    #pragma unroll
    for (int t = 0; t < T_STEPS; ++t) {
        f32x4 sa, sb;
        ma += xa[t];
        mb += xb[t];
        #pragma unroll
        for (int j = 0; j < 4; ++j) {
            sa[j] = (ma[j] - th > 0.f) ? 1.f : 0.f;
            ma[j] = (sa[j] != 0.f) ? 0.f : ma[j];
            sb[j] = (mb[j] - th > 0.f) ? 1.f : 0.f;
            mb[j] = (sb[j] != 0.f) ? 0.f : mb[j];
        }
        __builtin_nontemporal_store(sa, &out[(size_t)t * n4 + i0]);
        __builtin_nontemporal_store(sb, &out[(size_t)t * n4 + i1]);
    }
}

extern "C" void kernel_launch(void* const* d_in, const int* in_sizes, int n_in,
                              void* d_out, int out_size, void* d_ws, size_t ws_size,
                              hipStream_t stream) {
    const float* x   = (const float*)d_in[0];
    const float* thr = (const float*)d_in[1];
    float* out       = (float*)d_out;

    const int total = in_sizes[0];       // T*B*C*H*W = 33,554,432
    const int N     = total / T_STEPS;   // per-timestep elements = 4,194,304
    const int n4    = N / 4;             // vec4 count = 1,048,576

    const int threads = 256;
    const int blocks  = ((n4 / 2) + threads - 1) / threads;  // 2048

    if_scan_kernel<<<blocks, threads, 0, stream>>>(
        (const f32x4*)x, thr, (f32x4*)out, n4);
}

// Round 9
// 46.591 us; speedup vs baseline: 1.1253x; 1.0128x over previous
//
#include <hip/hip_runtime.h>

// Integrate-and-fire scan: x (T*B, C, H, W) f32, T=8, viewed as (T, N).
// One thread per float4 column, fully unrolled 8-step scan in registers.
// FINAL (R4 structure — best of 7 variants at 46.7 us):
//   - exact-fit grid (4096 x 256), no grid-stride loop: all 8 loads issue
//     at wave start; 2x wave-slot oversubscription backfills continuously.
//   - nontemporal stores: keeps dirty-eviction noise off HBM (-1.4 us).
//   - scan kept bit-exact vs reference (mem - th > 0, select-reset).
//
// Roofline evidence: 268 MB logical traffic / 46.7 us = 5.75 TB/s = 91% of
// the measured float4-copy ceiling (6.29 TB/s, same 1:1 R:W mix). VALUBusy
// 3.7%, zero LDS/bank activity. Refuted levers: nt store (R3: FETCH
// unchanged), system-scope store bypass (R5: incoherent with harness
// readback), nt loads (R7: regressed), 2-col split-half (R6), wave-adjacent
// 2-col page locality (R8), grid-stride persistent waves (R1).

#define T_STEPS 8

typedef float f32x4 __attribute__((ext_vector_type(4)));

__global__ __launch_bounds__(256) void if_scan_kernel(
    const f32x4* __restrict__ x,
    const float* __restrict__ thr_p,
    f32x4* __restrict__ out,
    int n4)   // N/4 vec4 elements per timestep
{
    const int i = blockIdx.x * blockDim.x + threadIdx.x;
    if (i >= n4) return;
    const float th = thr_p[0];

    // 8 independent loads issued up front (cacheable: input stays half
    // L3-resident across graph replays; steering attempts all failed).
    f32x4 xs[T_STEPS];
    #pragma unroll
    for (int t = 0; t < T_STEPS; ++t) {
        xs[t] = x[(size_t)t * n4 + i];
    }

    f32x4 mem = {0.f, 0.f, 0.f, 0.f};
    #pragma unroll
    for (int t = 0; t < T_STEPS; ++t) {
        f32x4 s;
        mem += xs[t];                                   // integrate
        #pragma unroll
        for (int j = 0; j < 4; ++j) {
            s[j]   = (mem[j] - th > 0.f) ? 1.f : 0.f;   // fire
            mem[j] = (s[j] != 0.f) ? 0.f : mem[j];      // hard reset
        }
        __builtin_nontemporal_store(s, &out[(size_t)t * n4 + i]);
    }
}

extern "C" void kernel_launch(void* const* d_in, const int* in_sizes, int n_in,
                              void* d_out, int out_size, void* d_ws, size_t ws_size,
                              hipStream_t stream) {
    const float* x   = (const float*)d_in[0];
    const float* thr = (const float*)d_in[1];
    float* out       = (float*)d_out;

    const int total = in_sizes[0];       // T*B*C*H*W = 33,554,432
    const int N     = total / T_STEPS;   // per-timestep elements = 4,194,304
    const int n4    = N / 4;             // vec4 count = 1,048,576

    const int threads = 256;
    const int blocks  = (n4 + threads - 1) / threads;   // 4096: exact fit

    if_scan_kernel<<<blocks, threads, 0, stream>>>(
        (const f32x4*)x, thr, (f32x4*)out, n4);
}